// Round 9
// baseline (220.722 us; speedup 1.0000x reference)
//
#include <hip/hip_runtime.h>
#include <stdint.h>

typedef unsigned short u16;
typedef unsigned int   u32;

#define Bn 4
#define Cc 512
#define Hh 96
#define Ww 96
#define HWc (Hh*Ww)   // 9216
#define AH 11
#define Rr 512
#define CP (Cc/2)     // 256 dwords per point (bf16 NHWC)

__device__ __forceinline__ u16 f2bf(float f){
  u32 u = __float_as_uint(f);
  u += 0x7fffu + ((u>>16)&1u);
  return (u16)(u>>16);
}
__device__ __forceinline__ u32 pk2(float a, float b){
  return (u32)f2bf(a) | ((u32)f2bf(b)<<16);
}

// ---- fp32 NCHW -> bf16-pair (u32) NHWC transpose; 128hw x 128c tile ----
// LDS: u32 tile[128*64], XOR-swizzled col' = cp ^ (hw>>2)  -> conflict-free
__global__ __launch_bounds__(256)
void transpose_kernel(const float* __restrict__ in, u32* __restrict__ out){
  __shared__ u32 tile[128*64];   // 32 KB
  const int t = threadIdx.x;
  const int hw0 = blockIdx.x*128, c0 = blockIdx.y*128, b = blockIdx.z;
  {
    const int q = t & 31, cp0 = t >> 5;           // q: hw quad, cp0: 0..7
    const float* ib = in + ((size_t)(b*Cc + c0))*HWc + hw0 + 4*q;
    #pragma unroll
    for (int p=0;p<8;++p){
      const int cp = cp0 + p*8;                   // 0..63 channel pair in tile
      const float* pa = ib + (size_t)(2*cp)*HWc;
      float4 A = *(const float4*)pa;
      float4 B = *(const float4*)(pa + HWc);
      const int cs = cp ^ q;                      // (4q+i)>>2 == q for i<4
      tile[(4*q+0)*64 + cs] = pk2(A.x,B.x);
      tile[(4*q+1)*64 + cs] = pk2(A.y,B.y);
      tile[(4*q+2)*64 + cs] = pk2(A.z,B.z);
      tile[(4*q+3)*64 + cs] = pk2(A.w,B.w);
    }
  }
  __syncthreads();
  {
    const int l = t & 63, wv = t >> 6;            // lane = cp, wave = row group
    u32* ob = out + ((size_t)b*HWc + hw0)*CP + (c0>>1) + l;
    #pragma unroll
    for (int k=0;k<32;++k){
      const int hw = wv*32 + k;
      ob[(size_t)hw*CP] = tile[hw*64 + (l ^ (hw>>2))];  // 256B contiguous store
    }
  }
}

// ---- fused RoIAlignAda + 3x3/s2 maxpool, NHWC bf16 ----
// 4 blocks per ROI: channel-half x ph-segment. bid = k*512 + r (k=0..3) so all
// four blocks of ROI r share bid%8 -> same XCD under round-robin dispatch
// (shared L2 footprint). 128 threads; thread t owns dword half*128+t.
// seg0: ph 0..4 -> oy 0..1 ; seg1: ph 4..10 -> oy 2..4.

template<int NPH, int NOY>
__device__ __forceinline__ void roi_seg_body(
    const u32* __restrict__ fbase,
    const int4* s_ro, const float4* s_rw,
    const int (*vo)[4], const float (*cwr)[4],
    float* __restrict__ s_out, int t, int LO)
{
  float2 awin[5];
  #pragma unroll 1
  for (int lp=0; lp<NPH; ++lp){
    const int ph = LO + lp;
    int4   r4 = s_ro[ph];
    float4 w4 = s_rw[ph];
    // scalar row bases (SGPR-pair addressing for the gathers)
    const u32* r0 = fbase + __builtin_amdgcn_readfirstlane(r4.x);
    const u32* r1 = fbase + __builtin_amdgcn_readfirstlane(r4.y);
    const u32* r2 = fbase + __builtin_amdgcn_readfirstlane(r4.z);
    const u32* r3 = fbase + __builtin_amdgcn_readfirstlane(r4.w);
    const float rw_[4] = {w4.x, w4.y, w4.z, w4.w};
    float2 binr[AH];
    #pragma unroll
    for (int pw=0; pw<AH; ++pw){
      u32 v[16];
      #pragma unroll
      for (int j=0;j<4;++j){
        v[0*4+j] = r0[vo[pw][j]];
        v[1*4+j] = r1[vo[pw][j]];
        v[2*4+j] = r2[vo[pw][j]];
        v[3*4+j] = r3[vo[pw][j]];
      }
      float ax=0.0f, ay=0.0f;
      #pragma unroll
      for (int i=0;i<4;++i)
        #pragma unroll
        for (int j=0;j<4;++j){
          float w = rw_[i]*cwr[pw][j];
          u32 d = v[i*4+j];
          ax = fmaf(w, __uint_as_float(d<<16),           ax);
          ay = fmaf(w, __uint_as_float(d & 0xffff0000u), ay);
        }
      binr[pw] = make_float2(ax, ay);
    }
    float2 rm[5];
    #pragma unroll
    for (int ox=0; ox<5; ++ox){
      rm[ox].x = fmaxf(fmaxf(binr[2*ox].x, binr[2*ox+1].x), binr[2*ox+2].x);
      rm[ox].y = fmaxf(fmaxf(binr[2*ox].y, binr[2*ox+1].y), binr[2*ox+2].y);
    }
    if (lp == 0){
      #pragma unroll
      for (int ox=0; ox<5; ++ox) awin[ox] = rm[ox];
    } else if (lp & 1){
      #pragma unroll
      for (int ox=0; ox<5; ++ox){
        awin[ox].x = fmaxf(awin[ox].x, rm[ox].x);
        awin[ox].y = fmaxf(awin[ox].y, rm[ox].y);
      }
    } else {
      const int ol = (lp-2) >> 1;
      #pragma unroll
      for (int ox=0; ox<5; ++ox){
        s_out[(2*t  )*(NOY*5) + ol*5 + ox] = fmaxf(awin[ox].x, rm[ox].x);
        s_out[(2*t+1)*(NOY*5) + ol*5 + ox] = fmaxf(awin[ox].y, rm[ox].y);
        awin[ox] = rm[ox];
      }
    }
  }
}

__global__ __launch_bounds__(128)
void roi_align_max_nhwc(const u32* __restrict__ feat,
                        const float* __restrict__ rois,
                        float* __restrict__ out)
{
  __shared__ __align__(16) int4   s_ro[AH];
  __shared__ __align__(16) float4 s_rw[AH];
  __shared__ __align__(16) int4   s_co[AH];
  __shared__ __align__(16) float4 s_cw[AH];
  __shared__ int s_b;
  __shared__ __align__(16) float s_out[256*15];   // 15 KB (seg1 full, seg0 2/3)

  const int t    = threadIdx.x;
  const int bid  = blockIdx.x;
  const int r    = bid & 511;
  const int k    = bid >> 9;        // 0..3, same XCD for all k of one ROI
  const int half = k & 1;
  const int seg  = k >> 1;

  if (t == 0){
    int b = (int)rois[r*5+0];
    s_b = min(max(b, 0), Bn-1);
  }

  // geometry: threads 0..10 -> rows (ph), threads 64..74 -> cols (pw)
  if (t < AH || (t >= 64 && t < 64+AH)){
    const bool isrow = (t < AH);
    const int  p = isrow ? t : t-64;
    const float* rp = rois + r*5;
    const float c1 = rp[isrow?2:1], c2 = rp[isrow?4:3];
    // replicate np float32 ops exactly (no fp contraction at validity boundaries)
    float lo  = __fmul_rn(c1, 0.125f);
    float hi  = __fmul_rn(c2, 0.125f);
    float ext = fmaxf(__fsub_rn(hi,lo), 0.0f);
    float bin = __fdiv_rn(ext, 10.0f);
    float ctr = __fadd_rn(lo, __fmul_rn((float)p, bin));
    float strd = fmaxf(1.0f, rintf(__fdiv_rn(bin, 3.0f)));   // half-even == jnp.round
    bool ok = (ctr >= 0.0f) && (ctr < 96.0f);
    int rws[6]; float wts[6]; int nv=0;
    #pragma unroll
    for (int s=0;s<3;++s){
      float cc = __fadd_rn(ctr, __fmul_rn((float)(s-1), strd));
      bool vv = (cc >= 0.0f) && (cc < 96.0f);
      float fl = fminf(fmaxf(floorf(cc),0.0f),94.0f);
      float fr = __fsub_rn(cc, fl);
      int ri = (int)fl;
      rws[2*s]=ri; rws[2*s+1]=ri+1;
      wts[2*s]  = vv ? __fsub_rn(1.0f,fr) : 0.0f;
      wts[2*s+1]= vv ? fr : 0.0f;
      nv += vv?1:0;
    }
    float sc = ok ? (1.0f/(float)nv) : 0.0f;   // folds center_ok + 1/cnt (separable)
    // dedupe-merge (stride==1 here => <=4 unique), pad to 4 with w=0
    int cr[4]={0,0,0,0}; float cwv[4]={0.0f,0.0f,0.0f,0.0f}; int n=0;
    for (int kk=0;kk<6;++kk){
      float wk=wts[kk]; if (wk==0.0f) continue;
      int rr=rws[kk]; bool fnd=false;
      for (int j=0;j<n;++j) if (cr[j]==rr){ cwv[j]+=wk; fnd=true; break; }
      if (!fnd && n<4){ cr[n]=rr; cwv[n]=wk; ++n; }
    }
    const int mul = isrow ? (Ww*CP) : CP;      // offsets in dwords
    if (isrow){
      s_ro[p] = make_int4(cr[0]*mul, cr[1]*mul, cr[2]*mul, cr[3]*mul);
      s_rw[p] = make_float4(cwv[0]*sc, cwv[1]*sc, cwv[2]*sc, cwv[3]*sc);
    } else {
      s_co[p] = make_int4(cr[0]*mul, cr[1]*mul, cr[2]*mul, cr[3]*mul);
      s_cw[p] = make_float4(cwv[0]*sc, cwv[1]*sc, cwv[2]*sc, cwv[3]*sc);
    }
  }
  __syncthreads();

  const u32* fbase = feat + (size_t)s_b*((size_t)HWc*CP);
  const int tb = half*128 + t;                 // this thread's dword lane

  // hoist column voffsets + weights into registers
  int   vo[AH][4]; float cwr[AH][4];
  #pragma unroll
  for (int pw=0; pw<AH; ++pw){
    int4 c4 = s_co[pw]; float4 w4 = s_cw[pw];
    vo[pw][0]=tb+c4.x; vo[pw][1]=tb+c4.y; vo[pw][2]=tb+c4.z; vo[pw][3]=tb+c4.w;
    cwr[pw][0]=w4.x; cwr[pw][1]=w4.y; cwr[pw][2]=w4.z; cwr[pw][3]=w4.w;
  }

  if (seg == 0) roi_seg_body<5,2>(fbase, s_ro, s_rw, vo, cwr, s_out, t, 0);
  else          roi_seg_body<7,3>(fbase, s_ro, s_rw, vo, cwr, s_out, t, 4);
  __syncthreads();

  // copy out this (half, seg) chunk: [256 ch][NOY*5]
  const int noy5 = (seg==0) ? 10 : 15;
  float* dst = out + (size_t)r*(Cc*25) + (size_t)half*(256*25) + (seg==0 ? 0 : 10);
  for (int kk=t; kk<256*noy5; kk+=128){
    int c = kk/noy5, j = kk - c*noy5;
    dst[c*25 + j] = s_out[kk];
  }
}

// ---- fallback: NCHW fp32 direct (known-correct, used only if ws too small) ----
__global__ __launch_bounds__(512, 1)
void roi_align_max_nchw(const float* __restrict__ feat,
                        const float* __restrict__ rois,
                        float* __restrict__ out)
{
  __shared__ int   s_roff[AH][6];
  __shared__ float s_rw  [AH][6];
  __shared__ int   s_coff[AH][6];
  __shared__ float s_cw  [AH][6];
  __shared__ int   s_b;
  __shared__ __align__(16) float s_out[Cc*25];

  const int t = threadIdx.x;
  const int r = blockIdx.x;

  if (t < AH*6){
    ((float*)s_rw)[t] = 0.0f;  ((int*)s_roff)[t] = 0;
    ((float*)s_cw)[t] = 0.0f;  ((int*)s_coff)[t] = 0;
  }
  if (t == 0){
    int b = (int)rois[r*5+0];
    s_b = min(max(b, 0), Bn-1);
  }
  __syncthreads();

  if (t < AH || (t >= 64 && t < 64+AH)){
    const bool isrow = (t < AH);
    const int  p = isrow ? t : t-64;
    const float* rp = rois + r*5;
    const float c1 = rp[isrow?2:1], c2 = rp[isrow?4:3];
    float lo  = __fmul_rn(c1, 0.125f);
    float hi  = __fmul_rn(c2, 0.125f);
    float ext = fmaxf(__fsub_rn(hi,lo), 0.0f);
    float bin = __fdiv_rn(ext, 10.0f);
    float ctr = __fadd_rn(lo, __fmul_rn((float)p, bin));
    float strd = fmaxf(1.0f, rintf(__fdiv_rn(bin, 3.0f)));
    bool ok = (ctr >= 0.0f) && (ctr < 96.0f);
    int rws[6]; float wts[6]; int nv=0;
    #pragma unroll
    for (int s=0;s<3;++s){
      float cc = __fadd_rn(ctr, __fmul_rn((float)(s-1), strd));
      bool vv = (cc >= 0.0f) && (cc < 96.0f);
      float fl = fminf(fmaxf(floorf(cc),0.0f),94.0f);
      float fr = __fsub_rn(cc, fl);
      int ri = (int)fl;
      rws[2*s]=ri; rws[2*s+1]=ri+1;
      wts[2*s]  = vv ? __fsub_rn(1.0f,fr) : 0.0f;
      wts[2*s+1]= vv ? fr : 0.0f;
      nv += vv?1:0;
    }
    float sc = ok ? (1.0f/(float)nv) : 0.0f;
    int cr[6]; float cw[6]; int n=0;
    for (int kk=0;kk<6;++kk){
      float wk=wts[kk]; if (wk==0.0f) continue;
      if (n>0 && cr[n-1]==rws[kk]) cw[n-1]+=wk;
      else { cr[n]=rws[kk]; cw[n]=wk; ++n; }
    }
    const int mul = isrow ? Ww : 1;
    for (int kk=0;kk<n;++kk){
      int off = cr[kk]*mul;
      float wv = cw[kk]*sc;
      if (isrow){ s_roff[p][kk]=off; s_rw[p][kk]=wv; }
      else      { s_coff[p][kk]=off; s_cw[p][kk]=wv; }
    }
  }
  __syncthreads();

  const float* f0 = feat + ((size_t)s_b*Cc + t)*HWc;
  float awin[5];
  for (int ph=0; ph<AH; ++ph){
    float binrow[AH];
    #pragma unroll
    for (int pw=0; pw<AH; ++pw){
      float acc = 0.0f;
      #pragma unroll
      for (int ai=0; ai<6; ++ai){
        float ra = s_rw[ph][ai];
        if (ra == 0.0f) continue;
        int ro = s_roff[ph][ai];
        #pragma unroll
        for (int bi=0; bi<6; ++bi){
          float cb = s_cw[pw][bi];
          if (cb == 0.0f) continue;
          acc = fmaf(ra*cb, f0[ro + s_coff[pw][bi]], acc);
        }
      }
      binrow[pw] = acc;
    }
    float rm[5];
    #pragma unroll
    for (int ox=0; ox<5; ++ox)
      rm[ox] = fmaxf(fmaxf(binrow[2*ox], binrow[2*ox+1]), binrow[2*ox+2]);
    if (ph == 0){
      #pragma unroll
      for (int ox=0; ox<5; ++ox) awin[ox] = rm[ox];
    } else if (ph & 1){
      #pragma unroll
      for (int ox=0; ox<5; ++ox) awin[ox] = fmaxf(awin[ox], rm[ox]);
    } else {
      int oy = (ph-2) >> 1;
      #pragma unroll
      for (int ox=0; ox<5; ++ox){
        s_out[t*25 + oy*5 + ox] = fmaxf(awin[ox], rm[ox]);
        awin[ox] = rm[ox];
      }
    }
  }
  __syncthreads();

  float4* dst = (float4*)(out + (size_t)r*(Cc*25));
  const float4* src = (const float4*)s_out;
  for (int kk=t; kk<(Cc*25)/4; kk+=512) dst[kk]=src[kk];
}

extern "C" void kernel_launch(void* const* d_in, const int* in_sizes, int n_in,
                              void* d_out, int out_size, void* d_ws, size_t ws_size,
                              hipStream_t stream)
{
  (void)in_sizes; (void)n_in; (void)out_size;
  const float* feat = (const float*)d_in[0];
  const float* rois = (const float*)d_in[1];
  float* out = (float*)d_out;
  const size_t need = (size_t)Bn*HWc*Cc*sizeof(u16);   // 37.75 MB bf16 NHWC
  if (ws_size >= need){
    u32* ws = (u32*)d_ws;
    dim3 g(HWc/128, Cc/128, Bn);
    transpose_kernel<<<g, 256, 0, stream>>>(feat, ws);
    roi_align_max_nhwc<<<Rr*4, 128, 0, stream>>>(ws, rois, out);
  } else {
    roi_align_max_nchw<<<Rr, 512, 0, stream>>>(feat, rois, out);
  }
}